// Round 18
// baseline (212.564 us; speedup 1.0000x reference)
//
#include <hip/hip_runtime.h>

typedef unsigned short u16;
typedef unsigned int u32;
typedef __bf16 bf16x8 __attribute__((ext_vector_type(8)));
typedef float f32x4 __attribute__((ext_vector_type(4)));

#define BDIM 4
#define TDIM 2048
#define EDIM 1024
#define HDIM 16
#define HS 64
#define MROWS (BDIM * TDIM)
#define FFNP 128   // FFN_HID=100 padded to 128

__device__ __forceinline__ u16 f2bf(float f) {
    __bf16 h = (__bf16)f;
    return __builtin_bit_cast(u16, h);
}

__device__ __forceinline__ float bf2f(u16 u) {
    return (float)__builtin_bit_cast(__bf16, u);
}

__device__ __forceinline__ void glds16(const void* g, void* l) {
    __builtin_amdgcn_global_load_lds(
        (__attribute__((address_space(1))) const void*)g,
        (__attribute__((address_space(3))) void*)l, 16, 0, 0);
}

// ---------- all 6 weight transposes (f32 -> bf16, optional zero-pad) ----------
__global__ __launch_bounds__(256) void transpose_all(
    const float* __restrict__ wq, const float* __restrict__ wk,
    const float* __restrict__ wv, const float* __restrict__ wproj,
    const float* __restrict__ w1, const float* __restrict__ w2,
    u16* __restrict__ wqkvt, u16* __restrict__ wpt,
    u16* __restrict__ w1t, u16* __restrict__ w2t)
{
    __shared__ u16 sm[64][72];
    const float* src; u16* dst;
    int K, N, Kpad, Npad;
    switch (blockIdx.z) {
        case 0: src = wq;    dst = wqkvt;                 K = N = Kpad = Npad = 1024; break;
        case 1: src = wk;    dst = wqkvt + 1024 * 1024;   K = N = Kpad = Npad = 1024; break;
        case 2: src = wv;    dst = wqkvt + 2 * 1024 * 1024; K = N = Kpad = Npad = 1024; break;
        case 3: src = wproj; dst = wpt;                   K = N = Kpad = Npad = 1024; break;
        case 4: src = w1;    dst = w1t; K = 1024; N = 100; Kpad = 1024; Npad = 128; break;
        default: src = w2;   dst = w2t; K = 100; N = 1024; Kpad = 128; Npad = 1024; break;
    }
    int k0 = blockIdx.x * 64, n0 = blockIdx.y * 64;
    if (k0 >= Kpad || n0 >= Npad) return;
    int tid = threadIdx.x;
#pragma unroll
    for (int i = 0; i < 16; i++) {
        int idx = i * 256 + tid;
        int kl = idx >> 6, nl = idx & 63;
        int k = k0 + kl, n = n0 + nl;
        float v = (k < K && n < N) ? src[(size_t)k * N + n] : 0.f;
        sm[kl][nl] = f2bf(v);
    }
    __syncthreads();
#pragma unroll
    for (int i = 0; i < 16; i++) {
        int idx = i * 256 + tid;
        int nl = idx >> 6, kl = idx & 63;
        int n = n0 + nl, k = k0 + kl;
        if (n < Npad && k < Kpad) dst[(size_t)n * Kpad + k] = sm[kl][nl];
    }
}

// ---------------- LayerNorm rows (f32 in -> bf16 out) -------------------------
__global__ __launch_bounds__(256) void ln_rows(
    const float* __restrict__ X, const float* __restrict__ G,
    const float* __restrict__ Bv, u16* __restrict__ H)
{
    int w = threadIdx.x >> 6, l = threadIdx.x & 63;
    int row = blockIdx.x * 4 + w;
    const float* xr = X + (size_t)row * EDIM;
    float4 v[4];
    float s = 0.f, s2 = 0.f;
#pragma unroll
    for (int i = 0; i < 4; i++) {
        v[i] = *(const float4*)&xr[l * 4 + i * 256];
        s += v[i].x + v[i].y + v[i].z + v[i].w;
        s2 += v[i].x * v[i].x + v[i].y * v[i].y + v[i].z * v[i].z + v[i].w * v[i].w;
    }
#pragma unroll
    for (int off = 1; off < 64; off <<= 1) {
        s += __shfl_xor(s, off, 64);
        s2 += __shfl_xor(s2, off, 64);
    }
    float mean = s * (1.f / EDIM);
    float var = s2 * (1.f / EDIM) - mean * mean;
    float rstd = rsqrtf(var + 1e-5f);
#pragma unroll
    for (int i = 0; i < 4; i++) {
        int c = l * 4 + i * 256;
        float4 gg = *(const float4*)&G[c];
        float4 bb = *(const float4*)&Bv[c];
        u16 o0 = f2bf((v[i].x - mean) * rstd * gg.x + bb.x);
        u16 o1 = f2bf((v[i].y - mean) * rstd * gg.y + bb.y);
        u16 o2 = f2bf((v[i].z - mean) * rstd * gg.z + bb.z);
        u16 o3 = f2bf((v[i].w - mean) * rstd * gg.w + bb.w);
        uint2 pk;
        pk.x = (u32)o0 | ((u32)o1 << 16);
        pk.y = (u32)o2 | ((u32)o3 << 16);
        *(uint2*)&H[(size_t)row * EDIM + c] = pk;
    }
}

// ---------------- LayerNorm rows (bf16 in -> bf16 out) ------------------------
__global__ __launch_bounds__(256) void ln_rows_b(
    const u16* __restrict__ X, const float* __restrict__ G,
    const float* __restrict__ Bv, u16* __restrict__ H)
{
    int w = threadIdx.x >> 6, l = threadIdx.x & 63;
    int row = blockIdx.x * 4 + w;
    const u16* xr = X + (size_t)row * EDIM;
    float v[16];
    float s = 0.f, s2 = 0.f;
#pragma unroll
    for (int i = 0; i < 2; i++) {
        bf16x8 u = *(const bf16x8*)&xr[l * 8 + i * 512];
#pragma unroll
        for (int e = 0; e < 8; e++) {
            float f = (float)u[e];
            v[i * 8 + e] = f;
            s += f; s2 += f * f;
        }
    }
#pragma unroll
    for (int off = 1; off < 64; off <<= 1) {
        s += __shfl_xor(s, off, 64);
        s2 += __shfl_xor(s2, off, 64);
    }
    float mean = s * (1.f / EDIM);
    float var = s2 * (1.f / EDIM) - mean * mean;
    float rstd = rsqrtf(var + 1e-5f);
#pragma unroll
    for (int i = 0; i < 2; i++) {
        int c = l * 8 + i * 512;
        float4 g0 = *(const float4*)&G[c];
        float4 g1 = *(const float4*)&G[c + 4];
        float4 b0 = *(const float4*)&Bv[c];
        float4 b1 = *(const float4*)&Bv[c + 4];
        float gg[8] = {g0.x, g0.y, g0.z, g0.w, g1.x, g1.y, g1.z, g1.w};
        float bb[8] = {b0.x, b0.y, b0.z, b0.w, b1.x, b1.y, b1.z, b1.w};
        uint4 pk;
        u32 o[8];
#pragma unroll
        for (int e = 0; e < 8; e++)
            o[e] = (u32)f2bf((v[i * 8 + e] - mean) * rstd * gg[e] + bb[e]);
        pk.x = o[0] | (o[1] << 16);
        pk.y = o[2] | (o[3] << 16);
        pk.z = o[4] | (o[5] << 16);
        pk.w = o[6] | (o[7] << 16);
        *(uint4*)&H[(size_t)row * EDIM + c] = pk;
    }
}

// ======= 256x256 8-phase GEMM — QK only: qk = hbuf x [wq|wk]^T ================
#define LDA4(d, mfb)                                                          \
    _Pragma("unroll") for (int mi = 0; mi < 4; mi++)                          \
    _Pragma("unroll") for (int ks = 0; ks < 2; ks++)                          \
        a[mi][ks] = *(const bf16x8*)&L[d][0][wm][((mfb + mi) * 16 + lr) * 64  \
                        + (((lg + 4 * ks) ^ (lr & 7)) << 3)];
#define LDB2(d, nfb)                                                          \
    _Pragma("unroll") for (int ni = 0; ni < 2; ni++)                          \
    _Pragma("unroll") for (int ks = 0; ks < 2; ks++)                          \
        b[ni][ks] = *(const bf16x8*)&L[d][1][wh][((wn & 1) * 64               \
                        + (nfb + ni) * 16 + lr) * 64                          \
                        + (((lg + 4 * ks) ^ (lr & 7)) << 3)];
#define MFMAQ(mfb, nfb)                                                       \
    _Pragma("unroll") for (int mi = 0; mi < 4; mi++)                          \
    _Pragma("unroll") for (int ni = 0; ni < 2; ni++)                          \
    _Pragma("unroll") for (int ks = 0; ks < 2; ks++)                          \
        acc[mfb + mi][nfb + ni] = __builtin_amdgcn_mfma_f32_16x16x32_bf16(    \
            a[mi][ks], b[ni][ks], acc[mfb + mi][nfb + ni], 0, 0, 0);
#define PH_SYNC1()                                                            \
    __builtin_amdgcn_s_barrier();                                             \
    asm volatile("s_waitcnt lgkmcnt(0)" ::: "memory");                        \
    __builtin_amdgcn_sched_barrier(0);                                        \
    __builtin_amdgcn_s_setprio(1);
#define PH_SYNC2()                                                            \
    __builtin_amdgcn_s_setprio(0);                                            \
    __builtin_amdgcn_s_barrier();
#define PH_SYNC2V(cond)                                                       \
    __builtin_amdgcn_s_setprio(0);                                            \
    if (cond) { asm volatile("s_waitcnt vmcnt(2)" ::: "memory"); }            \
    else      { asm volatile("s_waitcnt vmcnt(0)" ::: "memory"); }            \
    __builtin_amdgcn_s_barrier();

__global__ __launch_bounds__(512, 2) void gemm256_qk(
    const u16* __restrict__ A, const u16* __restrict__ Bt,
    u16* __restrict__ Cb)
{
    __shared__ u16 L[2][2][2][128 * 64];   // 128 KiB
    int id = blockIdx.x;
    int sw = (id & 7) * 32 + (id >> 3);    // XCD swizzle, bijective over 256
    int bx = sw % 32, by = sw / 32;
    const int m0 = bx * 256, n0 = by * 256;

    const int tid = threadIdx.x;
    const int w = tid >> 6, l = tid & 63;
    const int wm = w >> 2, wn = w & 3, wh = wn >> 1;
    const int lg = l >> 4, lr = l & 15;

    const int srow = w * 16 + (l >> 3);
    const int sch8 = ((l & 7) ^ (l >> 3)) * 8;   // pre-swizzled source chunk

    auto stA = [&](int d, int h, int t) {
        const u16* src = A + (size_t)(m0 + h * 128 + srow) * 1024 + t * 64 + sch8;
        u16* dst = &L[d][0][h][w * 1024];
        glds16(src, dst);
        glds16(src + (size_t)8 * 1024, dst + 512);
    };
    auto stB = [&](int d, int h, int t) {
        const u16* src = Bt + (size_t)(n0 + h * 128 + srow) * 1024 + t * 64 + sch8;
        u16* dst = &L[d][1][h][w * 1024];
        glds16(src, dst);
        glds16(src + (size_t)8 * 1024, dst + 512);
    };

    f32x4 acc[8][4];
#pragma unroll
    for (int i = 0; i < 8; i++)
#pragma unroll
        for (int j = 0; j < 4; j++) acc[i][j] = f32x4{0.f, 0.f, 0.f, 0.f};
    bf16x8 a[4][2], b[2][2];

    const int NI = 1024 >> 7;   // 8 iterations of 2 K-tiles

    stA(0, 0, 0); stA(0, 1, 0); stB(0, 0, 0); stB(0, 1, 0);
    stB(1, 0, 1);
    asm volatile("s_waitcnt vmcnt(2)" ::: "memory");
    __builtin_amdgcn_s_barrier();

#pragma unroll 1
    for (int j = 0; j < NI; j++) {
        const int t = 2 * j;
        const bool more = (j + 1 < NI);
        // ph1
        LDA4(0, 0); LDB2(0, 0);
        stA(1, 0, t + 1);
        PH_SYNC1(); MFMAQ(0, 0); PH_SYNC2();
        // ph2
        LDA4(0, 4);
        stA(1, 1, t + 1);
        PH_SYNC1(); MFMAQ(4, 0); PH_SYNC2();
        // ph3
        LDB2(0, 2);
        stB(1, 1, t + 1);
        PH_SYNC1(); MFMAQ(4, 2); PH_SYNC2();
        // ph4
        LDA4(0, 0);
        if (more) stB(0, 1, t + 2);
        PH_SYNC1(); MFMAQ(0, 2); PH_SYNC2V(more);
        // ph5
        LDA4(1, 0); LDB2(1, 0);
        if (more) stA(0, 0, t + 2);
        PH_SYNC1(); MFMAQ(0, 0); PH_SYNC2();
        // ph6
        LDA4(1, 4);
        if (more) stA(0, 1, t + 2);
        PH_SYNC1(); MFMAQ(4, 0); PH_SYNC2();
        // ph7
        LDB2(1, 2);
        if (more) stB(0, 0, t + 2);
        PH_SYNC1(); MFMAQ(4, 2); PH_SYNC2();
        // ph8
        LDA4(1, 0);
        if (more) stB(1, 0, t + 3);
        PH_SYNC1(); MFMAQ(0, 2); PH_SYNC2V(more);
    }

#pragma unroll
    for (int mf = 0; mf < 8; mf++) {
#pragma unroll
        for (int nf = 0; nf < 4; nf++) {
#pragma unroll
            for (int e = 0; e < 4; e++) {
                int row = m0 + wm * 128 + mf * 16 + lg * 4 + e;
                int col = n0 + wn * 64 + nf * 16 + lr;
                Cb[(size_t)row * 2048 + col] = f2bf(acc[mf][nf][e]);
            }
        }
    }
}

// ------- bf16 MFMA GEMM, Bt input ([N][ldb]), 128x128 tile, 2-phase dbuf ------
// MODE 2: x2b = bf16(resid_f32 + A*B + bias)        (proj, bf16 out)
// MODE 3: out = bf16resid + A*B + bias -> f32       (ffn2, final write)
// MODE 4: split-K partial -> bf16                   (ffn1)
// MODE 5: V^T producer (writes vt per-head transposed).
template <int MODE>
__global__ __launch_bounds__(256, 2) void gemm_bt(
    const u16* __restrict__ A, const u16* __restrict__ Bt,
    float* __restrict__ Cf,
    const void* __restrict__ resid, const float* __restrict__ bias,
    int M, int N, int K, int lda, int ldb, int mb)
{
    __shared__ u16 As[2][128 * 32];
    __shared__ u16 Bs[2][128 * 32];
    int bx, by;
    if constexpr (MODE == 4) {
        bx = blockIdx.x; by = blockIdx.y;
        int kz = blockIdx.z;
        A += kz * 256;
        Bt += kz * 256;
        Cf = (float*)((u16*)Cf + (size_t)kz * M * N);
    } else {
        int nwg = gridDim.x, id = blockIdx.x;
        int sw = (id & 7) * (nwg >> 3) + (id >> 3);   // XCD swizzle
        bx = sw % mb; by = sw / mb;
    }
    const int tid = threadIdx.x;
    const int w = tid >> 6, l = tid & 63;
    const int wr = w >> 1, wc = w & 1;
    const int lg = l >> 4, lr = l & 15;
    const int m0 = bx * 128, n0 = by * 128;

    f32x4 zero = {0.f, 0.f, 0.f, 0.f};
    f32x4 acc[4][4];
#pragma unroll
    for (int i = 0; i < 4; i++)
#pragma unroll
        for (int j = 0; j < 4; j++) acc[i][j] = zero;

    const u16* Ag = A + (size_t)(m0 + w * 16 + (l >> 2)) * lda + (l & 3) * 8;
    const u16* Bg = Bt + (size_t)(n0 + w * 16 + (l >> 2)) * ldb + (l & 3) * 8;

    auto stage = [&](int b, int k0) {
        glds16(Ag + k0, &As[b][w * 512]);
        glds16(Ag + k0 + (size_t)64 * lda, &As[b][w * 512 + 2048]);
        glds16(Bg + k0, &Bs[b][w * 512]);
        glds16(Bg + k0 + (size_t)64 * ldb, &Bs[b][w * 512 + 2048]);
    };
    auto compute = [&](int b) {
        bf16x8 af[4], bfr[4];
#pragma unroll
        for (int t = 0; t < 4; t++)
            af[t] = *(const bf16x8*)&As[b][(wr * 64 + t * 16 + lr) * 32 + lg * 8];
#pragma unroll
        for (int t = 0; t < 4; t++)
            bfr[t] = *(const bf16x8*)&Bs[b][(wc * 64 + t * 16 + lr) * 32 + lg * 8];
#pragma unroll
        for (int i = 0; i < 4; i++)
#pragma unroll
            for (int j = 0; j < 4; j++)
                acc[i][j] = __builtin_amdgcn_mfma_f32_16x16x32_bf16(
                    af[i], bfr[j], acc[i][j], 0, 0, 0);
    };

    stage(0, 0);
    __syncthreads();
    int cur = 0;
    for (int k0 = 32; k0 < K; k0 += 32) {
        stage(cur ^ 1, k0);
        compute(cur);
        __syncthreads();
        cur ^= 1;
    }
    compute(cur);

#pragma unroll
    for (int i = 0; i < 4; i++) {
#pragma unroll
        for (int j = 0; j < 4; j++) {
#pragma unroll
            for (int e = 0; e < 4; e++) {
                int row = m0 + wr * 64 + i * 16 + lg * 4 + e;
                int col = n0 + wc * 64 + j * 16 + lr;
                float v = acc[i][j][e];
                if constexpr (MODE == 2) {
                    size_t idx = (size_t)row * N + col;
                    ((u16*)Cf)[idx] =
                        f2bf(((const float*)resid)[idx] + v + bias[col]);
                } else if constexpr (MODE == 3) {
                    size_t idx = (size_t)row * N + col;
                    Cf[idx] = bf2f(((const u16*)resid)[idx]) + v + bias[col];
                } else if constexpr (MODE == 4) {
                    ((u16*)Cf)[(size_t)row * N + col] = f2bf(v);
                } else {  // MODE 5: vt writer
                    u16* vtp = (u16*)Cf;
                    int bq = col >> 11, tt = col & 2047;
                    vtp[((size_t)bq * 1024 + row) * 2048 + tt] = f2bf(v);
                }
            }
        }
    }
}

// ------------- ffn1 split-K reduce (bf16 partials): relu(sum4+bias) ----------
__global__ __launch_bounds__(256) void relu_reduce4(
    const u16* __restrict__ fp, const float* __restrict__ b1,
    u16* __restrict__ tb)
{
    const size_t CH = (size_t)MROWS * FFNP;
    size_t base = ((size_t)blockIdx.x * 256 + threadIdx.x) * 8;
    bf16x8 s0 = *(const bf16x8*)&fp[base];
    bf16x8 s1 = *(const bf16x8*)&fp[base + CH];
    bf16x8 s2 = *(const bf16x8*)&fp[base + 2 * CH];
    bf16x8 s3 = *(const bf16x8*)&fp[base + 3 * CH];
    int col = (int)(base & (FFNP - 1));
    u32 o[8];
#pragma unroll
    for (int j = 0; j < 8; j++) {
        float sv = (float)s0[j] + (float)s1[j] + (float)s2[j] + (float)s3[j];
        int c = col + j;
        float b = (c < 100) ? b1[c] : 0.f;
        o[j] = (u32)f2bf(fmaxf(sv + b, 0.f));
    }
    uint4 pk;
    pk.x = o[0] | (o[1] << 16);
    pk.y = o[2] | (o[3] << 16);
    pk.z = o[4] | (o[5] << 16);
    pk.w = o[6] | (o[7] << 16);
    *(uint4*)&tb[base] = pk;
}

// --- causal flash attention: 4 waves, QBLK=64, KVB=64, single-barrier dbuf ----
// B2 eliminated: restage of tile t+1's dead buffer moved to after B1 of tile t
// (a wave reaches B1(t) only after its tile-(t-1) LDS reads completed, so
// post-B1 the old buffer is dead block-wide). vmcnt re-derived: top-of-tile
// outstanding = current tile's own 4 loads -> vmcnt(0) (t=0: vmcnt(4) while
// tile1 in flight). One barrier per q-block end protects the next prologue.
__global__ __launch_bounds__(256, 4) void attn_fwd(
    const u16* __restrict__ qk, const u16* __restrict__ Vt,
    u16* __restrict__ Og)
{
    int xcd = blockIdx.x & 7;
    int j = blockIdx.x >> 3;          // 0..127
    int bh = xcd * 8 + (j & 7);
    int qp = j >> 3;                  // q-pair index 0..15
    int bb = bh >> 4, hh = bh & 15;

    int tid = threadIdx.x;
    int w = tid >> 6, l = tid & 63;
    int lg = l >> 4, lr = l & 15;

    const u16* Qb = qk + ((size_t)bb * TDIM) * 2048 + hh * HS;
    const u16* Kb = Qb + 1024;
    const u16* Vb = Vt + (size_t)bh * HS * TDIM;

    __shared__ u16 Ks[2][64 * 64];               // [kv][d] XOR-swizzled
    __shared__ u16 Vs[2][64 * 64];               // [d][kv] XOR-swizzled
    __shared__ __align__(16) u16 Ps[4][16 * 64]; // per-wave P, XOR-swizzled

    int srow = w * 16 + (l >> 3);             // staged row (16 rows/wave)
    int schunk = (l & 7) ^ ((l >> 3) & 7);    // pre-swizzled source chunk
    u16* Pw = Ps[w];
    int sbase = (l & 48) + lg * 4;

    const float QSCL = 0.045084227f;          // 2^-5 * log2(e)

#pragma unroll 1
    for (int qi = 0; qi < 2; qi++) {
        int qb = (qi == 0 ? qp : 31 - qp) * 64;
        int q_abs = qb + w * 16 + lr;
        int wlo = qb + w * 16;
        int nt = qb / 64 + 1;                  // kv tiles for this q-block

        bf16x8 qf[2];
        qf[0] = *(const bf16x8*)&Qb[(size_t)q_abs * 2048 + lg * 8];
        qf[1] = *(const bf16x8*)&Qb[(size_t)q_abs * 2048 + 32 + lg * 8];
#pragma unroll
        for (int i = 0; i < 8; i++) {
            qf[0][i] = (__bf16)((float)qf[0][i] * QSCL);
            qf[1][i] = (__bf16)((float)qf[1][i] * QSCL);
        }

        f32x4 zero = {0.f, 0.f, 0.f, 0.f};
        f32x4 oacc[4];
#pragma unroll
        for (int dt = 0; dt < 4; dt++) oacc[dt] = zero;
        float lpart = 0.f;                     // per-lane partial denominator

        auto stage = [&](int b, int kv0) {
            glds16(Kb + (size_t)(kv0 + srow) * 2048 + schunk * 8, &Ks[b][w * 1024]);
            glds16(Kb + (size_t)(kv0 + srow + 8) * 2048 + schunk * 8,
                   &Ks[b][w * 1024 + 512]);
            glds16(Vb + (size_t)srow * TDIM + kv0 + schunk * 8, &Vs[b][w * 1024]);
            glds16(Vb + (size_t)(srow + 8) * TDIM + kv0 + schunk * 8,
                   &Vs[b][w * 1024 + 512]);
        };

        stage(0, 0);
        if (nt > 1) stage(1, 64);
#pragma unroll 1
        for (int t = 0; t < nt; t++) {
            int kv0 = t * 64;
            int buf = t & 1;
            // top-of-tile: wait own loads for tile t (issued >=1 tile ago)
            if (t == 0 && nt > 1) { asm volatile("s_waitcnt vmcnt(4)" ::: "memory"); }
            else                  { asm volatile("s_waitcnt vmcnt(0)" ::: "memory"); }
            __builtin_amdgcn_sched_barrier(0);
            __builtin_amdgcn_s_barrier();      // B1: tile t staged; buf^1 dead
            // restage the buffer tile t-1 used with tile t+1's successor
            if (t >= 1 && t + 1 < nt) stage(buf ^ 1, kv0 + 64);
            const u16* Kc = Ks[buf];
            const u16* Vc = Vs[buf];
            f32x4 sc[4];
#pragma unroll
            for (int ct = 0; ct < 4; ct++) sc[ct] = zero;
            __builtin_amdgcn_s_setprio(1);
#pragma unroll
            for (int ct = 0; ct < 4; ct++) {
#pragma unroll
                for (int dc = 0; dc < 2; dc++) {
                    bf16x8 kf = *(const bf16x8*)&Kc[(ct * 16 + lr) * 64 +
                                                    (((lg + 4 * dc) ^ (lr & 7)) << 3)];
                    sc[ct] = __builtin_amdgcn_mfma_f32_16x16x32_bf16(
                        kf, qf[dc], sc[ct], 0, 0, 0);
                }
            }
            __builtin_amdgcn_s_setprio(0);
            // prefetch V fragments (independent of P; overlaps softmax VALU)
            bf16x8 vfr[2][4];
#pragma unroll
            for (int m = 0; m < 2; m++)
#pragma unroll
                for (int dt = 0; dt < 4; dt++)
                    vfr[m][dt] = *(const bf16x8*)&Vc[(dt * 16 + lr) * 64 +
                                                     (((lg + 4 * m) ^ (lr & 7)) << 3)];
            // softmax, log2 domain, fixed shift 0; mask only diag tiles
            float p[16];
            if (kv0 + 63 > wlo) {
#pragma unroll
                for (int ct = 0; ct < 4; ct++) {
#pragma unroll
                    for (int e = 0; e < 4; e++) {
                        float v = sc[ct][e];
                        if (kv0 + ct * 16 + lg * 4 + e > q_abs) v = -1e30f;
                        p[ct * 4 + e] = v;
                    }
                }
            } else {
#pragma unroll
                for (int ct = 0; ct < 4; ct++) {
#pragma unroll
                    for (int e = 0; e < 4; e++) p[ct * 4 + e] = sc[ct][e];
                }
            }
            float psum = 0.f;
#pragma unroll
            for (int i = 0; i < 16; i++) {
                p[i] = __builtin_amdgcn_exp2f(p[i]);   // exp2(-1e30) = 0
                psum += p[i];
            }
            lpart += psum;
            // write P[q=lr][kv]: one ds_write_b64 per quadrant (8B aligned)
#pragma unroll
            for (int ct = 0; ct < 4; ct++) {
                uint2 pr;
                pr.x = (u32)f2bf(p[ct * 4 + 0]) | ((u32)f2bf(p[ct * 4 + 1]) << 16);
                pr.y = (u32)f2bf(p[ct * 4 + 2]) | ((u32)f2bf(p[ct * 4 + 3]) << 16);
                int kvb = ct * 16 + lg * 4;
                int idx = lr * 64 + ((((kvb >> 3) ^ (lr & 7)) << 3) | (kvb & 7));
                *(uint2*)&Pw[idx] = pr;
            }
            asm volatile("s_waitcnt lgkmcnt(0)" ::: "memory");
            __builtin_amdgcn_sched_barrier(0);
            __builtin_amdgcn_s_setprio(1);
#pragma unroll
            for (int m = 0; m < 2; m++) {
                bf16x8 pa = *(const bf16x8*)&Pw[lr * 64 + (((lg + 4 * m) ^ (lr & 7)) << 3)];
#pragma unroll
                for (int dt = 0; dt < 4; dt++) {
                    oacc[dt] = __builtin_amdgcn_mfma_f32_16x16x32_bf16(
                        pa, vfr[m][dt], oacc[dt], 0, 0, 0);
                }
            }
            __builtin_amdgcn_s_setprio(0);
        }
        // end-of-qblock: all waves' K/V reads done before next prologue restage
        __builtin_amdgcn_s_barrier();
        // single end-of-block denominator reduce
        float lsum = lpart;
        lsum += __shfl_xor(lsum, 16, 64);
        lsum += __shfl_xor(lsum, 32, 64);
        float lT[4];
#pragma unroll
        for (int e = 0; e < 4; e++) lT[e] = __shfl(lsum, sbase + e, 64);
#pragma unroll
        for (int dt = 0; dt < 4; dt++) {
#pragma unroll
            for (int e = 0; e < 4; e++) {
                int row = qb + w * 16 + lg * 4 + e;
                Og[((size_t)bb * TDIM + row) * EDIM + hh * HS + dt * 16 + lr] =
                    f2bf(oacc[dt][e] / lT[e]);
            }
        }
    }
}

// -----------------------------------------------------------------------------
extern "C" void kernel_launch(void* const* d_in, const int* in_sizes, int n_in,
                              void* d_out, int out_size, void* d_ws, size_t ws_size,
                              hipStream_t stream)
{
    const float* x     = (const float*)d_in[0];
    const float* wq    = (const float*)d_in[1];
    const float* wk    = (const float*)d_in[2];
    const float* wv    = (const float*)d_in[3];
    const float* wproj = (const float*)d_in[4];
    const float* bproj = (const float*)d_in[5];
    const float* w1    = (const float*)d_in[6];
    const float* b1    = (const float*)d_in[7];
    const float* w2    = (const float*)d_in[8];
    const float* b2    = (const float*)d_in[9];
    const float* ln1g  = (const float*)d_in[10];
    const float* ln1b  = (const float*)d_in[11];
    const float* ln2g  = (const float*)d_in[12];
    const float* ln2b  = (const float*)d_in[13];
    float* out = (float*)d_out;

    char* ws = (char*)d_ws;
    size_t off = 0;
    auto alloc = [&](size_t bytes) -> void* {
        void* p = (void*)(ws + off);
        off += (bytes + 255) & ~(size_t)255;
        return p;
    };
    u16* hbuf = (u16*)alloc((size_t)MROWS * EDIM * 2);
    u16* qk   = (u16*)alloc((size_t)MROWS * 2048 * 2);   // fused q|k
    u16* attb = (u16*)alloc((size_t)MROWS * EDIM * 2);
    u16* vt   = (u16*)alloc((size_t)MROWS * EDIM * 2);
    u16* x2b  = (u16*)alloc((size_t)MROWS * EDIM * 2);   // bf16 residual stream
    u16* wqkvt = (u16*)alloc((size_t)3072 * EDIM * 2);   // q|k|v transposed
    u16* wpt  = (u16*)alloc((size_t)EDIM * EDIM * 2);
    u16* w1t  = (u16*)alloc((size_t)FFNP * EDIM * 2);
    u16* w2t  = (u16*)alloc((size_t)EDIM * FFNP * 2);
    // FFN-phase aliases (attention-phase buffers dead by then)
    u16* fpb = (u16*)qk;   // 4 x MROWS x FFNP bf16 = 8.4 MB <= qk (33.5 MB)
    u16* tb  = vt;

    transpose_all<<<dim3(16, 16, 6), 256, 0, stream>>>(
        wq, wk, wv, wproj, w1, w2, wqkvt, wpt, w1t, w2t);

    ln_rows<<<MROWS / 4, 256, 0, stream>>>(x, ln1g, ln1b, hbuf);
    // QK: 256^2 8-phase, 256 blocks = exactly 1 round
    gemm256_qk<<<dim3(256), 512, 0, stream>>>(hbuf, wqkvt, qk);
    // V^T: 128^2 2-phase, 512 blocks; writes vt via per-head remap
    gemm_bt<5><<<dim3(512), 256, 0, stream>>>(wqkvt + (size_t)2048 * 1024, hbuf,
                                              (float*)vt, nullptr, nullptr,
                                              1024, 8192, 1024, 1024, 1024, 8);
    attn_fwd<<<dim3(1024), 256, 0, stream>>>(qk, vt, attb);
    // proj + residual -> x2 (bf16)
    gemm_bt<2><<<dim3(512), 256, 0, stream>>>(attb, wpt, (float*)x2b, x, bproj,
                                              MROWS, EDIM, EDIM, EDIM, EDIM, 64);
    ln_rows_b<<<MROWS / 4, 256, 0, stream>>>(x2b, ln2g, ln2b, hbuf);
    // FFN1 split-K x4 bf16 partials -> fpb
    gemm_bt<4><<<dim3(64, 1, 4), 256, 0, stream>>>(hbuf, w1t, (float*)fpb, nullptr,
                                                   nullptr, MROWS, FFNP, 256,
                                                   EDIM, EDIM, 64);
    relu_reduce4<<<dim3(MROWS * FFNP / 2048), 256, 0, stream>>>(fpb, b1, tb);
    // FFN2: out = x2b + tb x w2t + b2  (final f32 write)
    gemm_bt<3><<<dim3(512), 256, 0, stream>>>(tb, w2t, out, x2b, b2,
                                              MROWS, EDIM, FFNP, FFNP, FFNP, 64);
}

// Round 19
// 210.534 us; speedup vs baseline: 1.0096x; 1.0096x over previous
//
#include <hip/hip_runtime.h>

typedef unsigned short u16;
typedef unsigned int u32;
typedef __bf16 bf16x8 __attribute__((ext_vector_type(8)));
typedef float f32x4 __attribute__((ext_vector_type(4)));

#define BDIM 4
#define TDIM 2048
#define EDIM 1024
#define HDIM 16
#define HS 64
#define MROWS (BDIM * TDIM)
#define FFNP 128   // FFN_HID=100 padded to 128

__device__ __forceinline__ u16 f2bf(float f) {
    __bf16 h = (__bf16)f;
    return __builtin_bit_cast(u16, h);
}

__device__ __forceinline__ float bf2f(u16 u) {
    return (float)__builtin_bit_cast(__bf16, u);
}

__device__ __forceinline__ void glds16(const void* g, void* l) {
    __builtin_amdgcn_global_load_lds(
        (__attribute__((address_space(1))) const void*)g,
        (__attribute__((address_space(3))) void*)l, 16, 0, 0);
}

// ---------- all 6 weight transposes (f32 -> bf16, optional zero-pad) ----------
__global__ __launch_bounds__(256) void transpose_all(
    const float* __restrict__ wq, const float* __restrict__ wk,
    const float* __restrict__ wv, const float* __restrict__ wproj,
    const float* __restrict__ w1, const float* __restrict__ w2,
    u16* __restrict__ wqkvt, u16* __restrict__ wpt,
    u16* __restrict__ w1t, u16* __restrict__ w2t)
{
    __shared__ u16 sm[64][72];
    const float* src; u16* dst;
    int K, N, Kpad, Npad;
    switch (blockIdx.z) {
        case 0: src = wq;    dst = wqkvt;                 K = N = Kpad = Npad = 1024; break;
        case 1: src = wk;    dst = wqkvt + 1024 * 1024;   K = N = Kpad = Npad = 1024; break;
        case 2: src = wv;    dst = wqkvt + 2 * 1024 * 1024; K = N = Kpad = Npad = 1024; break;
        case 3: src = wproj; dst = wpt;                   K = N = Kpad = Npad = 1024; break;
        case 4: src = w1;    dst = w1t; K = 1024; N = 100; Kpad = 1024; Npad = 128; break;
        default: src = w2;   dst = w2t; K = 100; N = 1024; Kpad = 128; Npad = 1024; break;
    }
    int k0 = blockIdx.x * 64, n0 = blockIdx.y * 64;
    if (k0 >= Kpad || n0 >= Npad) return;
    int tid = threadIdx.x;
#pragma unroll
    for (int i = 0; i < 16; i++) {
        int idx = i * 256 + tid;
        int kl = idx >> 6, nl = idx & 63;
        int k = k0 + kl, n = n0 + nl;
        float v = (k < K && n < N) ? src[(size_t)k * N + n] : 0.f;
        sm[kl][nl] = f2bf(v);
    }
    __syncthreads();
#pragma unroll
    for (int i = 0; i < 16; i++) {
        int idx = i * 256 + tid;
        int nl = idx >> 6, kl = idx & 63;
        int n = n0 + nl, k = k0 + kl;
        if (n < Npad && k < Kpad) dst[(size_t)n * Kpad + k] = sm[kl][nl];
    }
}

// ---------------- LayerNorm rows (f32 in -> bf16 out) -------------------------
__global__ __launch_bounds__(256) void ln_rows(
    const float* __restrict__ X, const float* __restrict__ G,
    const float* __restrict__ Bv, u16* __restrict__ H)
{
    int w = threadIdx.x >> 6, l = threadIdx.x & 63;
    int row = blockIdx.x * 4 + w;
    const float* xr = X + (size_t)row * EDIM;
    float4 v[4];
    float s = 0.f, s2 = 0.f;
#pragma unroll
    for (int i = 0; i < 4; i++) {
        v[i] = *(const float4*)&xr[l * 4 + i * 256];
        s += v[i].x + v[i].y + v[i].z + v[i].w;
        s2 += v[i].x * v[i].x + v[i].y * v[i].y + v[i].z * v[i].z + v[i].w * v[i].w;
    }
#pragma unroll
    for (int off = 1; off < 64; off <<= 1) {
        s += __shfl_xor(s, off, 64);
        s2 += __shfl_xor(s2, off, 64);
    }
    float mean = s * (1.f / EDIM);
    float var = s2 * (1.f / EDIM) - mean * mean;
    float rstd = rsqrtf(var + 1e-5f);
#pragma unroll
    for (int i = 0; i < 4; i++) {
        int c = l * 4 + i * 256;
        float4 gg = *(const float4*)&G[c];
        float4 bb = *(const float4*)&Bv[c];
        u16 o0 = f2bf((v[i].x - mean) * rstd * gg.x + bb.x);
        u16 o1 = f2bf((v[i].y - mean) * rstd * gg.y + bb.y);
        u16 o2 = f2bf((v[i].z - mean) * rstd * gg.z + bb.z);
        u16 o3 = f2bf((v[i].w - mean) * rstd * gg.w + bb.w);
        uint2 pk;
        pk.x = (u32)o0 | ((u32)o1 << 16);
        pk.y = (u32)o2 | ((u32)o3 << 16);
        *(uint2*)&H[(size_t)row * EDIM + c] = pk;
    }
}

// ---------------- LayerNorm rows (bf16 in -> bf16 out) ------------------------
__global__ __launch_bounds__(256) void ln_rows_b(
    const u16* __restrict__ X, const float* __restrict__ G,
    const float* __restrict__ Bv, u16* __restrict__ H)
{
    int w = threadIdx.x >> 6, l = threadIdx.x & 63;
    int row = blockIdx.x * 4 + w;
    const u16* xr = X + (size_t)row * EDIM;
    float v[16];
    float s = 0.f, s2 = 0.f;
#pragma unroll
    for (int i = 0; i < 2; i++) {
        bf16x8 u = *(const bf16x8*)&xr[l * 8 + i * 512];
#pragma unroll
        for (int e = 0; e < 8; e++) {
            float f = (float)u[e];
            v[i * 8 + e] = f;
            s += f; s2 += f * f;
        }
    }
#pragma unroll
    for (int off = 1; off < 64; off <<= 1) {
        s += __shfl_xor(s, off, 64);
        s2 += __shfl_xor(s2, off, 64);
    }
    float mean = s * (1.f / EDIM);
    float var = s2 * (1.f / EDIM) - mean * mean;
    float rstd = rsqrtf(var + 1e-5f);
#pragma unroll
    for (int i = 0; i < 2; i++) {
        int c = l * 8 + i * 512;
        float4 g0 = *(const float4*)&G[c];
        float4 g1 = *(const float4*)&G[c + 4];
        float4 b0 = *(const float4*)&Bv[c];
        float4 b1 = *(const float4*)&Bv[c + 4];
        float gg[8] = {g0.x, g0.y, g0.z, g0.w, g1.x, g1.y, g1.z, g1.w};
        float bb[8] = {b0.x, b0.y, b0.z, b0.w, b1.x, b1.y, b1.z, b1.w};
        uint4 pk;
        u32 o[8];
#pragma unroll
        for (int e = 0; e < 8; e++)
            o[e] = (u32)f2bf((v[i * 8 + e] - mean) * rstd * gg[e] + bb[e]);
        pk.x = o[0] | (o[1] << 16);
        pk.y = o[2] | (o[3] << 16);
        pk.z = o[4] | (o[5] << 16);
        pk.w = o[6] | (o[7] << 16);
        *(uint4*)&H[(size_t)row * EDIM + c] = pk;
    }
}

// ======= 256x256 8-phase GEMM — QK only: qk = hbuf x [wq|wk]^T ================
#define LDA4(d, mfb)                                                          \
    _Pragma("unroll") for (int mi = 0; mi < 4; mi++)                          \
    _Pragma("unroll") for (int ks = 0; ks < 2; ks++)                          \
        a[mi][ks] = *(const bf16x8*)&L[d][0][wm][((mfb + mi) * 16 + lr) * 64  \
                        + (((lg + 4 * ks) ^ (lr & 7)) << 3)];
#define LDB2(d, nfb)                                                          \
    _Pragma("unroll") for (int ni = 0; ni < 2; ni++)                          \
    _Pragma("unroll") for (int ks = 0; ks < 2; ks++)                          \
        b[ni][ks] = *(const bf16x8*)&L[d][1][wh][((wn & 1) * 64               \
                        + (nfb + ni) * 16 + lr) * 64                          \
                        + (((lg + 4 * ks) ^ (lr & 7)) << 3)];
#define MFMAQ(mfb, nfb)                                                       \
    _Pragma("unroll") for (int mi = 0; mi < 4; mi++)                          \
    _Pragma("unroll") for (int ni = 0; ni < 2; ni++)                          \
    _Pragma("unroll") for (int ks = 0; ks < 2; ks++)                          \
        acc[mfb + mi][nfb + ni] = __builtin_amdgcn_mfma_f32_16x16x32_bf16(    \
            a[mi][ks], b[ni][ks], acc[mfb + mi][nfb + ni], 0, 0, 0);
#define PH_SYNC1()                                                            \
    __builtin_amdgcn_s_barrier();                                             \
    asm volatile("s_waitcnt lgkmcnt(0)" ::: "memory");                        \
    __builtin_amdgcn_sched_barrier(0);                                        \
    __builtin_amdgcn_s_setprio(1);
#define PH_SYNC2()                                                            \
    __builtin_amdgcn_s_setprio(0);                                            \
    __builtin_amdgcn_s_barrier();
#define PH_SYNC2V(cond)                                                       \
    __builtin_amdgcn_s_setprio(0);                                            \
    if (cond) { asm volatile("s_waitcnt vmcnt(2)" ::: "memory"); }            \
    else      { asm volatile("s_waitcnt vmcnt(0)" ::: "memory"); }            \
    __builtin_amdgcn_s_barrier();

__global__ __launch_bounds__(512, 2) void gemm256_qk(
    const u16* __restrict__ A, const u16* __restrict__ Bt,
    u16* __restrict__ Cb)
{
    __shared__ u16 L[2][2][2][128 * 64];   // 128 KiB
    int id = blockIdx.x;
    int sw = (id & 7) * 32 + (id >> 3);    // XCD swizzle, bijective over 256
    int bx = sw % 32, by = sw / 32;
    const int m0 = bx * 256, n0 = by * 256;

    const int tid = threadIdx.x;
    const int w = tid >> 6, l = tid & 63;
    const int wm = w >> 2, wn = w & 3, wh = wn >> 1;
    const int lg = l >> 4, lr = l & 15;

    const int srow = w * 16 + (l >> 3);
    const int sch8 = ((l & 7) ^ (l >> 3)) * 8;   // pre-swizzled source chunk

    auto stA = [&](int d, int h, int t) {
        const u16* src = A + (size_t)(m0 + h * 128 + srow) * 1024 + t * 64 + sch8;
        u16* dst = &L[d][0][h][w * 1024];
        glds16(src, dst);
        glds16(src + (size_t)8 * 1024, dst + 512);
    };
    auto stB = [&](int d, int h, int t) {
        const u16* src = Bt + (size_t)(n0 + h * 128 + srow) * 1024 + t * 64 + sch8;
        u16* dst = &L[d][1][h][w * 1024];
        glds16(src, dst);
        glds16(src + (size_t)8 * 1024, dst + 512);
    };

    f32x4 acc[8][4];
#pragma unroll
    for (int i = 0; i < 8; i++)
#pragma unroll
        for (int j = 0; j < 4; j++) acc[i][j] = f32x4{0.f, 0.f, 0.f, 0.f};
    bf16x8 a[4][2], b[2][2];

    const int NI = 1024 >> 7;   // 8 iterations of 2 K-tiles

    stA(0, 0, 0); stA(0, 1, 0); stB(0, 0, 0); stB(0, 1, 0);
    stB(1, 0, 1);
    asm volatile("s_waitcnt vmcnt(2)" ::: "memory");
    __builtin_amdgcn_s_barrier();

#pragma unroll 1
    for (int j = 0; j < NI; j++) {
        const int t = 2 * j;
        const bool more = (j + 1 < NI);
        // ph1
        LDA4(0, 0); LDB2(0, 0);
        stA(1, 0, t + 1);
        PH_SYNC1(); MFMAQ(0, 0); PH_SYNC2();
        // ph2
        LDA4(0, 4);
        stA(1, 1, t + 1);
        PH_SYNC1(); MFMAQ(4, 0); PH_SYNC2();
        // ph3
        LDB2(0, 2);
        stB(1, 1, t + 1);
        PH_SYNC1(); MFMAQ(4, 2); PH_SYNC2();
        // ph4
        LDA4(0, 0);
        if (more) stB(0, 1, t + 2);
        PH_SYNC1(); MFMAQ(0, 2); PH_SYNC2V(more);
        // ph5
        LDA4(1, 0); LDB2(1, 0);
        if (more) stA(0, 0, t + 2);
        PH_SYNC1(); MFMAQ(0, 0); PH_SYNC2();
        // ph6
        LDA4(1, 4);
        if (more) stA(0, 1, t + 2);
        PH_SYNC1(); MFMAQ(4, 0); PH_SYNC2();
        // ph7
        LDB2(1, 2);
        if (more) stB(0, 0, t + 2);
        PH_SYNC1(); MFMAQ(4, 2); PH_SYNC2();
        // ph8
        LDA4(1, 0);
        if (more) stB(1, 0, t + 3);
        PH_SYNC1(); MFMAQ(0, 2); PH_SYNC2V(more);
    }

#pragma unroll
    for (int mf = 0; mf < 8; mf++) {
#pragma unroll
        for (int nf = 0; nf < 4; nf++) {
#pragma unroll
            for (int e = 0; e < 4; e++) {
                int row = m0 + wm * 128 + mf * 16 + lg * 4 + e;
                int col = n0 + wn * 64 + nf * 16 + lr;
                Cb[(size_t)row * 2048 + col] = f2bf(acc[mf][nf][e]);
            }
        }
    }
}

// ------- bf16 MFMA GEMM, Bt input ([N][ldb]), 128x128 tile, 2-phase dbuf ------
// MODE 2: x2b = bf16(resid_f32 + A*B + bias)        (proj, bf16 out)
// MODE 3: out = bf16resid + A*B + bias -> f32       (ffn2, final write)
// MODE 4: split-K partial -> bf16                   (ffn1)
// MODE 5: V^T producer (writes vt per-head transposed).
template <int MODE>
__global__ __launch_bounds__(256, 2) void gemm_bt(
    const u16* __restrict__ A, const u16* __restrict__ Bt,
    float* __restrict__ Cf,
    const void* __restrict__ resid, const float* __restrict__ bias,
    int M, int N, int K, int lda, int ldb, int mb)
{
    __shared__ u16 As[2][128 * 32];
    __shared__ u16 Bs[2][128 * 32];
    int bx, by;
    if constexpr (MODE == 4) {
        bx = blockIdx.x; by = blockIdx.y;
        int kz = blockIdx.z;
        A += kz * 256;
        Bt += kz * 256;
        Cf = (float*)((u16*)Cf + (size_t)kz * M * N);
    } else {
        int nwg = gridDim.x, id = blockIdx.x;
        int sw = (id & 7) * (nwg >> 3) + (id >> 3);   // XCD swizzle
        bx = sw % mb; by = sw / mb;
    }
    const int tid = threadIdx.x;
    const int w = tid >> 6, l = tid & 63;
    const int wr = w >> 1, wc = w & 1;
    const int lg = l >> 4, lr = l & 15;
    const int m0 = bx * 128, n0 = by * 128;

    f32x4 zero = {0.f, 0.f, 0.f, 0.f};
    f32x4 acc[4][4];
#pragma unroll
    for (int i = 0; i < 4; i++)
#pragma unroll
        for (int j = 0; j < 4; j++) acc[i][j] = zero;

    const u16* Ag = A + (size_t)(m0 + w * 16 + (l >> 2)) * lda + (l & 3) * 8;
    const u16* Bg = Bt + (size_t)(n0 + w * 16 + (l >> 2)) * ldb + (l & 3) * 8;

    auto stage = [&](int b, int k0) {
        glds16(Ag + k0, &As[b][w * 512]);
        glds16(Ag + k0 + (size_t)64 * lda, &As[b][w * 512 + 2048]);
        glds16(Bg + k0, &Bs[b][w * 512]);
        glds16(Bg + k0 + (size_t)64 * ldb, &Bs[b][w * 512 + 2048]);
    };
    auto compute = [&](int b) {
        bf16x8 af[4], bfr[4];
#pragma unroll
        for (int t = 0; t < 4; t++)
            af[t] = *(const bf16x8*)&As[b][(wr * 64 + t * 16 + lr) * 32 + lg * 8];
#pragma unroll
        for (int t = 0; t < 4; t++)
            bfr[t] = *(const bf16x8*)&Bs[b][(wc * 64 + t * 16 + lr) * 32 + lg * 8];
#pragma unroll
        for (int i = 0; i < 4; i++)
#pragma unroll
            for (int j = 0; j < 4; j++)
                acc[i][j] = __builtin_amdgcn_mfma_f32_16x16x32_bf16(
                    af[i], bfr[j], acc[i][j], 0, 0, 0);
    };

    stage(0, 0);
    __syncthreads();
    int cur = 0;
    for (int k0 = 32; k0 < K; k0 += 32) {
        stage(cur ^ 1, k0);
        compute(cur);
        __syncthreads();
        cur ^= 1;
    }
    compute(cur);

#pragma unroll
    for (int i = 0; i < 4; i++) {
#pragma unroll
        for (int j = 0; j < 4; j++) {
#pragma unroll
            for (int e = 0; e < 4; e++) {
                int row = m0 + wr * 64 + i * 16 + lg * 4 + e;
                int col = n0 + wc * 64 + j * 16 + lr;
                float v = acc[i][j][e];
                if constexpr (MODE == 2) {
                    size_t idx = (size_t)row * N + col;
                    ((u16*)Cf)[idx] =
                        f2bf(((const float*)resid)[idx] + v + bias[col]);
                } else if constexpr (MODE == 3) {
                    size_t idx = (size_t)row * N + col;
                    Cf[idx] = bf2f(((const u16*)resid)[idx]) + v + bias[col];
                } else if constexpr (MODE == 4) {
                    ((u16*)Cf)[(size_t)row * N + col] = f2bf(v);
                } else {  // MODE 5: vt writer
                    u16* vtp = (u16*)Cf;
                    int bq = col >> 11, tt = col & 2047;
                    vtp[((size_t)bq * 1024 + row) * 2048 + tt] = f2bf(v);
                }
            }
        }
    }
}

// ------------- ffn1 split-K reduce (bf16 partials): relu(sum4+bias) ----------
__global__ __launch_bounds__(256) void relu_reduce4(
    const u16* __restrict__ fp, const float* __restrict__ b1,
    u16* __restrict__ tb)
{
    const size_t CH = (size_t)MROWS * FFNP;
    size_t base = ((size_t)blockIdx.x * 256 + threadIdx.x) * 8;
    bf16x8 s0 = *(const bf16x8*)&fp[base];
    bf16x8 s1 = *(const bf16x8*)&fp[base + CH];
    bf16x8 s2 = *(const bf16x8*)&fp[base + 2 * CH];
    bf16x8 s3 = *(const bf16x8*)&fp[base + 3 * CH];
    int col = (int)(base & (FFNP - 1));
    u32 o[8];
#pragma unroll
    for (int j = 0; j < 8; j++) {
        float sv = (float)s0[j] + (float)s1[j] + (float)s2[j] + (float)s3[j];
        int c = col + j;
        float b = (c < 100) ? b1[c] : 0.f;
        o[j] = (u32)f2bf(fmaxf(sv + b, 0.f));
    }
    uint4 pk;
    pk.x = o[0] | (o[1] << 16);
    pk.y = o[2] | (o[3] << 16);
    pk.z = o[4] | (o[5] << 16);
    pk.w = o[6] | (o[7] << 16);
    *(uint4*)&tb[base] = pk;
}

// --- causal flash attention: 4 waves, QBLK=64, KVB=64, counted-vmcnt dbuf -----
// (r15-measured configuration — the session's verified best at 66us.)
__global__ __launch_bounds__(256, 4) void attn_fwd(
    const u16* __restrict__ qk, const u16* __restrict__ Vt,
    u16* __restrict__ Og)
{
    int xcd = blockIdx.x & 7;
    int j = blockIdx.x >> 3;          // 0..127
    int bh = xcd * 8 + (j & 7);
    int qp = j >> 3;                  // q-pair index 0..15
    int bb = bh >> 4, hh = bh & 15;

    int tid = threadIdx.x;
    int w = tid >> 6, l = tid & 63;
    int lg = l >> 4, lr = l & 15;

    const u16* Qb = qk + ((size_t)bb * TDIM) * 2048 + hh * HS;
    const u16* Kb = Qb + 1024;
    const u16* Vb = Vt + (size_t)bh * HS * TDIM;

    __shared__ u16 Ks[2][64 * 64];               // [kv][d] XOR-swizzled
    __shared__ u16 Vs[2][64 * 64];               // [d][kv] XOR-swizzled
    __shared__ __align__(16) u16 Ps[4][16 * 64]; // per-wave P, XOR-swizzled

    int srow = w * 16 + (l >> 3);             // staged row (16 rows/wave)
    int schunk = (l & 7) ^ ((l >> 3) & 7);    // pre-swizzled source chunk
    u16* Pw = Ps[w];
    int sbase = (l & 48) + lg * 4;

    const float QSCL = 0.045084227f;          // 2^-5 * log2(e)

#pragma unroll 1
    for (int qi = 0; qi < 2; qi++) {
        int qb = (qi == 0 ? qp : 31 - qp) * 64;
        int q_abs = qb + w * 16 + lr;
        int wlo = qb + w * 16;
        int nt = qb / 64 + 1;                  // kv tiles for this q-block

        bf16x8 qf[2];
        qf[0] = *(const bf16x8*)&Qb[(size_t)q_abs * 2048 + lg * 8];
        qf[1] = *(const bf16x8*)&Qb[(size_t)q_abs * 2048 + 32 + lg * 8];
#pragma unroll
        for (int i = 0; i < 8; i++) {
            qf[0][i] = (__bf16)((float)qf[0][i] * QSCL);
            qf[1][i] = (__bf16)((float)qf[1][i] * QSCL);
        }

        f32x4 zero = {0.f, 0.f, 0.f, 0.f};
        f32x4 oacc[4];
#pragma unroll
        for (int dt = 0; dt < 4; dt++) oacc[dt] = zero;
        float lpart = 0.f;                     // per-lane partial denominator

        auto stage = [&](int b, int kv0) {
            glds16(Kb + (size_t)(kv0 + srow) * 2048 + schunk * 8, &Ks[b][w * 1024]);
            glds16(Kb + (size_t)(kv0 + srow + 8) * 2048 + schunk * 8,
                   &Ks[b][w * 1024 + 512]);
            glds16(Vb + (size_t)srow * TDIM + kv0 + schunk * 8, &Vs[b][w * 1024]);
            glds16(Vb + (size_t)(srow + 8) * TDIM + kv0 + schunk * 8,
                   &Vs[b][w * 1024 + 512]);
        };

        stage(0, 0);
        if (nt > 1) stage(1, 64);
#pragma unroll 1
        for (int t = 0; t < nt; t++) {
            int kv0 = t * 64;
            int buf = t & 1;
            if (t + 1 < nt) { asm volatile("s_waitcnt vmcnt(4)" ::: "memory"); }
            else            { asm volatile("s_waitcnt vmcnt(0)" ::: "memory"); }
            __builtin_amdgcn_sched_barrier(0);
            __builtin_amdgcn_s_barrier();      // cross-wave: tile t fully staged
            const u16* Kc = Ks[buf];
            const u16* Vc = Vs[buf];
            f32x4 sc[4];
#pragma unroll
            for (int ct = 0; ct < 4; ct++) sc[ct] = zero;
            __builtin_amdgcn_s_setprio(1);
#pragma unroll
            for (int ct = 0; ct < 4; ct++) {
#pragma unroll
                for (int dc = 0; dc < 2; dc++) {
                    bf16x8 kf = *(const bf16x8*)&Kc[(ct * 16 + lr) * 64 +
                                                    (((lg + 4 * dc) ^ (lr & 7)) << 3)];
                    sc[ct] = __builtin_amdgcn_mfma_f32_16x16x32_bf16(
                        kf, qf[dc], sc[ct], 0, 0, 0);
                }
            }
            __builtin_amdgcn_s_setprio(0);
            // prefetch V fragments (independent of P; overlaps softmax VALU)
            bf16x8 vfr[2][4];
#pragma unroll
            for (int m = 0; m < 2; m++)
#pragma unroll
                for (int dt = 0; dt < 4; dt++)
                    vfr[m][dt] = *(const bf16x8*)&Vc[(dt * 16 + lr) * 64 +
                                                     (((lg + 4 * m) ^ (lr & 7)) << 3)];
            // softmax, log2 domain, fixed shift 0; mask only diag tiles
            float p[16];
            if (kv0 + 63 > wlo) {
#pragma unroll
                for (int ct = 0; ct < 4; ct++) {
#pragma unroll
                    for (int e = 0; e < 4; e++) {
                        float v = sc[ct][e];
                        if (kv0 + ct * 16 + lg * 4 + e > q_abs) v = -1e30f;
                        p[ct * 4 + e] = v;
                    }
                }
            } else {
#pragma unroll
                for (int ct = 0; ct < 4; ct++) {
#pragma unroll
                    for (int e = 0; e < 4; e++) p[ct * 4 + e] = sc[ct][e];
                }
            }
            float psum = 0.f;
#pragma unroll
            for (int i = 0; i < 16; i++) {
                p[i] = __builtin_amdgcn_exp2f(p[i]);   // exp2(-1e30) = 0
                psum += p[i];
            }
            lpart += psum;
            // write P[q=lr][kv]: one ds_write_b64 per quadrant (8B aligned)
#pragma unroll
            for (int ct = 0; ct < 4; ct++) {
                uint2 pr;
                pr.x = (u32)f2bf(p[ct * 4 + 0]) | ((u32)f2bf(p[ct * 4 + 1]) << 16);
                pr.y = (u32)f2bf(p[ct * 4 + 2]) | ((u32)f2bf(p[ct * 4 + 3]) << 16);
                int kvb = ct * 16 + lg * 4;
                int idx = lr * 64 + ((((kvb >> 3) ^ (lr & 7)) << 3) | (kvb & 7));
                *(uint2*)&Pw[idx] = pr;
            }
            asm volatile("s_waitcnt lgkmcnt(0)" ::: "memory");
            __builtin_amdgcn_sched_barrier(0);
            __builtin_amdgcn_s_setprio(1);
#pragma unroll
            for (int m = 0; m < 2; m++) {
                bf16x8 pa = *(const bf16x8*)&Pw[lr * 64 + (((lg + 4 * m) ^ (lr & 7)) << 3)];
#pragma unroll
                for (int dt = 0; dt < 4; dt++) {
                    oacc[dt] = __builtin_amdgcn_mfma_f32_16x16x32_bf16(
                        pa, vfr[m][dt], oacc[dt], 0, 0, 0);
                }
            }
            __builtin_amdgcn_s_setprio(0);
            __builtin_amdgcn_s_barrier();      // WAR: all waves done with buf
            if (t + 2 < nt) stage(buf, kv0 + 128);
        }
        // single end-of-block denominator reduce
        float lsum = lpart;
        lsum += __shfl_xor(lsum, 16, 64);
        lsum += __shfl_xor(lsum, 32, 64);
        float lT[4];
#pragma unroll
        for (int e = 0; e < 4; e++) lT[e] = __shfl(lsum, sbase + e, 64);
#pragma unroll
        for (int dt = 0; dt < 4; dt++) {
#pragma unroll
            for (int e = 0; e < 4; e++) {
                int row = qb + w * 16 + lg * 4 + e;
                Og[((size_t)bb * TDIM + row) * EDIM + hh * HS + dt * 16 + lr] =
                    f2bf(oacc[dt][e] / lT[e]);
            }
        }
    }
}

// -----------------------------------------------------------------------------
extern "C" void kernel_launch(void* const* d_in, const int* in_sizes, int n_in,
                              void* d_out, int out_size, void* d_ws, size_t ws_size,
                              hipStream_t stream)
{
    const float* x     = (const float*)d_in[0];
    const float* wq    = (const float*)d_in[1];
    const float* wk    = (const float*)d_in[2];
    const float* wv    = (const float*)d_in[3];
    const float* wproj = (const float*)d_in[4];
    const float* bproj = (const float*)d_in[5];
    const float* w1    = (const float*)d_in[6];
    const float* b1    = (const float*)d_in[7];
    const float* w2    = (const float*)d_in[8];
    const float* b2    = (const float*)d_in[9];
    const float* ln1g  = (const float*)d_in[10];
    const float* ln1b  = (const float*)d_in[11];
    const float* ln2g  = (const float*)d_in[12];
    const float* ln2b  = (const float*)d_in[13];
    float* out = (float*)d_out;

    char* ws = (char*)d_ws;
    size_t off = 0;
    auto alloc = [&](size_t bytes) -> void* {
        void* p = (void*)(ws + off);
        off += (bytes + 255) & ~(size_t)255;
        return p;
    };
    u16* hbuf = (u16*)alloc((size_t)MROWS * EDIM * 2);
    u16* qk   = (u16*)alloc((size_t)MROWS * 2048 * 2);   // fused q|k
    u16* attb = (u16*)alloc((size_t)MROWS * EDIM * 2);
    u16* vt   = (u16*)alloc((size_t)MROWS * EDIM * 2);
    u16* x2b  = (u16*)alloc((size_t)MROWS * EDIM * 2);   // bf16 residual stream
    u16* wqkvt = (u16*)alloc((size_t)3072 * EDIM * 2);   // q|k|v transposed
    u16* wpt  = (u16*)alloc((size_t)EDIM * EDIM * 2);
    u16* w1t  = (u16*)alloc((size_t)FFNP * EDIM * 2);
    u16* w2t  = (u16*)alloc((size_t)EDIM * FFNP * 2);
    // FFN-phase aliases (attention-phase buffers dead by then)
    u16* fpb = (u16*)qk;   // 4 x MROWS x FFNP bf16 = 8.4 MB <= qk (33.5 MB)
    u16* tb  = vt;

    transpose_all<<<dim3(16, 16, 6), 256, 0, stream>>>(
        wq, wk, wv, wproj, w1, w2, wqkvt, wpt, w1t, w2t);

    ln_rows<<<MROWS / 4, 256, 0, stream>>>(x, ln1g, ln1b, hbuf);
    // QK: 256^2 8-phase, 256 blocks = exactly 1 round
    gemm256_qk<<<dim3(256), 512, 0, stream>>>(hbuf, wqkvt, qk);
    // V^T: 128^2 2-phase, 512 blocks; writes vt via per-head remap
    gemm_bt<5><<<dim3(512), 256, 0, stream>>>(wqkvt + (size_t)2048 * 1024, hbuf,
                                              (float*)vt, nullptr, nullptr,
                                              1024, 8192, 1024, 1024, 1024, 8);
    attn_fwd<<<dim3(1024), 256, 0, stream>>>(qk, vt, attb);
    // proj + residual -> x2 (bf16)
    gemm_bt<2><<<dim3(512), 256, 0, stream>>>(attb, wpt, (float*)x2b, x, bproj,
                                              MROWS, EDIM, EDIM, EDIM, EDIM, 64);
    ln_rows_b<<<MROWS / 4, 256, 0, stream>>>(x2b, ln2g, ln2b, hbuf);
    // FFN1 split-K x4 bf16 partials -> fpb
    gemm_bt<4><<<dim3(64, 1, 4), 256, 0, stream>>>(hbuf, w1t, (float*)fpb, nullptr,
                                                   nullptr, MROWS, FFNP, 256,
                                                   EDIM, EDIM, 64);
    relu_reduce4<<<dim3(MROWS * FFNP / 2048), 256, 0, stream>>>(fpb, b1, tb);
    // FFN2: out = x2b + tb x w2t + b2  (final f32 write)
    gemm_bt<3><<<dim3(512), 256, 0, stream>>>(tb, w2t, out, x2b, b2,
                                              MROWS, EDIM, FFNP, FFNP, FFNP, 64);
}